// Round 8
// baseline (117.334 us; speedup 1.0000x reference)
//
#include <hip/hip_runtime.h>

#define NROWS  8
#define NPIX   262144         // 512*512
#define K1_BPR 256            // compute: 1024 px/block, grid 2048
#define KC_BPR 128            // collect: 2048 px/block, grid 1024
#define HB8    256            // 8-bit histogram bins per row

// ctrl dwords: [0..7] = per-row done count (compute), [8] = collect done count
#define CTRL_ROW 0
#define CTRL_COL 8
#define CTRL_DW  32

// monotonic float->uint map (ascending float == ascending uint)
__device__ __forceinline__ unsigned int fkey(float x){
  unsigned int u = __float_as_uint(x);
  return (u & 0x80000000u) ? ~u : (u | 0x80000000u);
}

// binary softmax with a single exp
__device__ __forceinline__ void softmax2(float a0, float a1,
    float& lp0, float& lp1, float& p0, float& p1){
  float d  = a1 - a0;
  float ad = -fabsf(d);
  float e  = __expf(ad);
  float s  = 1.0f + e;
  float ls = __logf(s);
  float rs = __builtin_amdgcn_rcpf(s);
  float lpM = -ls,  lpm = ad - ls;
  float pM  = rs,   pm  = e * rs;
  bool g = (d >= 0.0f);
  lp1 = g ? lpM : lpm;  lp0 = g ? lpm : lpM;
  p1  = g ? pM  : pm;   p0  = g ? pm  : pM;
}

__device__ __forceinline__ float focal2(float tt, float lp0, float lp1,
                                        float p0, float p1){
  float q1 = 1.0f - p1, q0 = 1.0f - p0;
  return -(tt * q1 * q1 * lp1) - ((1.0f - tt) * q0 * q0 * lp0);
}

__device__ __forceinline__ unsigned kTop(const float* frp){
  return (unsigned)((1.0 - (double)(*frp)) * (double)NPIX);   // 209715
}

// custom zero (runtime fillBuffer is slow/unpredictable for small fills)
__global__ __launch_bounds__(256) void k_zero(unsigned int* __restrict__ p, int n){
  int i = blockIdx.x * 256 + threadIdx.x;
  int stride = gridDim.x * 256;
  for (; i < n; i += stride) p[i] = 0u;
}

// fused: loss compute + pack + 256-bin wave-ballot LDS hist (losses occupy
// ~10 exponent-level bins -> short aggregation loop; 4096-bin version cost
// 65us in round 7 from ~50 distinct bins/wave) + last-arriver row scan.
// Packed word: [31:20]=key12  [19]=target  [18:0]=l3 bits (exp8+man10, rnd)
__global__ __launch_bounds__(256) void k_compute(
    const float* __restrict__ in1, const float* __restrict__ in2,
    const float* __restrict__ in3, const int* __restrict__ tgt,
    const float* __restrict__ kdwp, const float* __restrict__ frp,
    unsigned int* __restrict__ packed, unsigned int* __restrict__ ghist,
    unsigned int* ctrl,
    unsigned int* __restrict__ selP8, unsigned int* __restrict__ selKrem)
{
  __shared__ unsigned lh[HB8];         // 1 KB block-local histogram / scan
  __shared__ unsigned lastFlag;
  const int t = threadIdx.x;
  lh[t] = 0;
  __syncthreads();

  const int blk   = blockIdx.x;
  const int row   = blk >> 8;                       // / K1_BPR
  const int chunk = (blk & (K1_BPR - 1)) * (NPIX / K1_BPR);
  const int base  = chunk + 4 * t;
  const float kdw = *kdwp;
  const float w1  = (float)(1.0 - (double)kdw);

  const size_t ro2 = (size_t)row * 2 * NPIX;
  const size_t ro1 = (size_t)row * NPIX;

  float4 x10 = *(const float4*)(in1 + ro2 + base);
  float4 x11 = *(const float4*)(in1 + ro2 + NPIX + base);
  float4 x20 = *(const float4*)(in2 + ro2 + base);
  float4 x21 = *(const float4*)(in2 + ro2 + NPIX + base);
  float4 x30 = *(const float4*)(in3 + ro2 + base);
  float4 x31 = *(const float4*)(in3 + ro2 + NPIX + base);
  int4   tg  = *(const int4*)(tgt + ro1 + base);

  float a10[4] = {x10.x, x10.y, x10.z, x10.w};
  float a11[4] = {x11.x, x11.y, x11.z, x11.w};
  float a20[4] = {x20.x, x20.y, x20.z, x20.w};
  float a21[4] = {x21.x, x21.y, x21.z, x21.w};
  float a30[4] = {x30.x, x30.y, x30.z, x30.w};
  float a31[4] = {x31.x, x31.y, x31.z, x31.w};
  int   tgv[4] = {tg.x, tg.y, tg.z, tg.w};

  unsigned pw[4];
  #pragma unroll
  for (int j = 0; j < 4; ++j){
    float tt = (float)tgv[j];
    float lp10, lp11, p10, p11; softmax2(a10[j], a11[j], lp10, lp11, p10, p11);
    float lp20, lp21, p20, p21; softmax2(a20[j], a21[j], lp20, lp21, p20, p21);
    float lp30, lp31, p30, p31; softmax2(a30[j], a31[j], lp30, lp31, p30, p31);
    float l1 = focal2(tt, lp10, lp11, p10, p11);
    float l2 = focal2(tt, lp20, lp21, p20, p21);
    float l3 = focal2(tt, lp30, lp31, p30, p31);
    float kdl12 = p10 * (lp10 - lp20) + p11 * (lp11 - lp21);
    float kdl21 = p20 * (lp20 - lp10) + p21 * (lp21 - lp11);
    float loss  = w1 * (l1 + l2 + l3) + kdw * (kdl12 + kdl21);
    unsigned k12 = fkey(loss) >> 20;
    // l3 >= 0: keep exp8+man10, round-to-nearest via +0x1000 before shift
    unsigned lb = __float_as_uint(l3) + 0x1000u;
    pw[j] = (k12 << 20) | (((unsigned)tgv[j]) << 19) | ((lb >> 13) & 0x7FFFFu);
  }
  *(uint4*)(packed + ro1 + base) = make_uint4(pw[0], pw[1], pw[2], pw[3]);

  // wave-ballot aggregated 256-bin histogram: ONE LDS atomic per distinct
  // bin per wave; ~10 distinct bins -> ~10 iterations
  const int lane = t & 63;
  #pragma unroll
  for (int j = 0; j < 4; ++j){
    unsigned bin = pw[j] >> 24;
    unsigned long long rem = ~0ull;
    while (rem){
      int lead = __ffsll(rem) - 1;
      unsigned leadBin = (unsigned)__shfl((int)bin, lead);
      unsigned long long same = __ballot(bin == leadBin);
      if (lane == lead) atomicAdd(&lh[leadBin], (unsigned)__popcll(same));
      rem &= ~same;
    }
  }
  __syncthreads();

  // flush block-local hist -> global (one aggregated atomic per hot bin)
  unsigned int* gh = ghist + (size_t)row * HB8;
  unsigned lv = lh[t];
  if (lv) atomicAdd(&gh[t], lv);
  __syncthreads();
  if (t == 0){
    __threadfence();                       // release hist/packed
    unsigned old = atomicAdd(&ctrl[CTRL_ROW + row], 1u);
    lastFlag = (old == K1_BPR - 1) ? 1u : 0u;
  }
  __syncthreads();
  if (!lastFlag) return;
  __threadfence();                         // acquire other blocks' hist

  // ---- last block of the row: 8-bit threshold bin via parallel scan ----
  unsigned v = gh[t];
  lh[t] = v; __syncthreads();
  unsigned run = v;
  #pragma unroll
  for (int off = 1; off < 256; off <<= 1){
    unsigned add = (t >= off) ? lh[t - off] : 0u;
    __syncthreads();
    run += add; lh[t] = run;
    __syncthreads();
  }
  const unsigned k0 = kTop(frp);
  unsigned inc = run, exc = run - v;
  if (exc < k0 && inc >= k0){              // exactly one thread
    selP8[row]   = (unsigned)t;
    selKrem[row] = k0 - exc;               // count to take from this bin
  }
}

// collect: below-bin sums + 16-sub-bin (key12) stats for the tie bin +
// total-target sum; last-arriver does frac-weighted final reduction -> out
__global__ __launch_bounds__(256) void k_collect(
    const unsigned int* __restrict__ packed,
    const unsigned int* __restrict__ selP8,
    const unsigned int* __restrict__ selKrem,
    const float* __restrict__ frp,
    float* __restrict__ pB3, unsigned int* __restrict__ pBT,
    unsigned int* __restrict__ pAT,
    unsigned int* __restrict__ gscnt, float* __restrict__ gsl3,
    unsigned int* __restrict__ gstg,
    unsigned int* ctrl, float* __restrict__ out)
{
  __shared__ unsigned s_cnt[16];
  __shared__ float    s_l3[16];
  __shared__ unsigned s_tg[16];
  __shared__ float wf[4];
  __shared__ int   wi[8];
  __shared__ double dd[12];
  __shared__ unsigned lastFlag;
  const int t = threadIdx.x, lane = t & 63, wid = t >> 6;
  const int blk   = blockIdx.x;
  const int row   = blk >> 7;                       // / KC_BPR
  const int chunk = (blk & (KC_BPR - 1)) * (NPIX / KC_BPR);
  const unsigned T8 = selP8[row];
  const size_t ro = (size_t)row * NPIX;
  if (t < 16){ s_cnt[t] = 0; s_l3[t] = 0.0f; s_tg[t] = 0; }
  __syncthreads();

  float b3 = 0.0f; int bt = 0, at = 0;
  #pragma unroll
  for (int it = 0; it < 2; ++it){
    int base = chunk + it * 1024 + 4 * t;
    uint4 w = *(const uint4*)(packed + ro + base);
    unsigned a[4] = {w.x, w.y, w.z, w.w};
    #pragma unroll
    for (int j = 0; j < 4; ++j){
      unsigned k8 = a[j] >> 24;
      float l3 = __uint_as_float((a[j] & 0x7FFFFu) << 13);
      int   tv = (int)((a[j] >> 19) & 1u);
      at += tv;
      if (k8 < T8){ b3 += l3; bt += tv; }
      else if (k8 == T8){
        unsigned sub = (a[j] >> 20) & 15u;     // key12 refinement
        atomicAdd(&s_cnt[sub], 1u);
        atomicAdd(&s_l3[sub], l3);
        if (tv) atomicAdd(&s_tg[sub], 1u);
      }
    }
  }
  #pragma unroll
  for (int o = 32; o; o >>= 1){
    b3 += __shfl_down(b3, o); bt += __shfl_down(bt, o); at += __shfl_down(at, o);
  }
  if (lane == 0){ wf[wid] = b3; wi[wid] = bt; wi[4 + wid] = at; }
  __syncthreads();
  if (t < 16){
    if (s_cnt[t]) atomicAdd(&gscnt[row * 16 + t], s_cnt[t]);
    if (s_l3[t] != 0.0f) atomicAdd(&gsl3[row * 16 + t], s_l3[t]);
    if (s_tg[t])  atomicAdd(&gstg[row * 16 + t], s_tg[t]);
  }
  if (t == 0){
    pB3[blk] = wf[0] + wf[1] + wf[2] + wf[3];
    pBT[blk] = (unsigned)(wi[0] + wi[1] + wi[2] + wi[3]);
    pAT[blk] = (unsigned)(wi[4] + wi[5] + wi[6] + wi[7]);
  }
  __syncthreads();              // all global atomics/stores issued + drained
  if (t == 0){
    __threadfence();                       // release partials + sub-hists
    unsigned old = atomicAdd(&ctrl[CTRL_COL], 1u);
    lastFlag = (old == NROWS * KC_BPR - 1) ? 1u : 0u;
  }
  __syncthreads();
  if (!lastFlag) return;
  __threadfence();                         // acquire all partials

  // ---- per-row tie resolution (16 sub-bins, frac-weighted crossing bin) ----
  double tie3 = 0.0, tieT = 0.0;
  if (t < NROWS){
    const int r = t;
    const unsigned kRem = selKrem[r];
    unsigned cum = 0;
    for (int s2 = 0; s2 < 16; ++s2){
      unsigned c = gscnt[r * 16 + s2];
      if (c){
        unsigned take = 0;
        if (kRem > cum){
          unsigned avail = kRem - cum;
          take = (avail < c) ? avail : c;
        }
        if (take){
          double fr = (double)take / (double)c;
          tie3 += fr * (double)gsl3[r * 16 + s2];
          tieT += fr * (double)gstg[r * 16 + s2];
        }
        cum += c;
      }
    }
  }

  // ---- global sums over block partials ----
  double S3 = tie3, ST = tieT, TT = 0.0;
  for (int i = t; i < NROWS * KC_BPR; i += 256){
    S3 += (double)pB3[i]; ST += (double)pBT[i]; TT += (double)pAT[i];
  }
  #pragma unroll
  for (int o = 32; o; o >>= 1){
    S3 += __shfl_down(S3, o); ST += __shfl_down(ST, o); TT += __shfl_down(TT, o);
  }
  if (lane == 0){ dd[wid] = S3; dd[4 + wid] = ST; dd[8 + wid] = TT; }
  __syncthreads();
  if (t == 0){
    double s0 = dd[0] + dd[1] + dd[2] + dd[3];
    double s1 = dd[4] + dd[5] + dd[6] + dd[7];
    double st = dd[8] + dd[9] + dd[10] + dd[11];
    out[0] = (float)(s0 / ((double)NROWS * (double)kTop(frp)));
    out[1] = (float)(s1 / st);
  }
}

extern "C" void kernel_launch(void* const* d_in, const int* in_sizes, int n_in,
                              void* d_out, int out_size, void* d_ws, size_t ws_size,
                              hipStream_t stream)
{
  const float* in1  = (const float*)d_in[0];
  const float* in2  = (const float*)d_in[1];
  const float* in3  = (const float*)d_in[2];
  const int*   tgt  = (const int*)d_in[3];
  const float* frp  = (const float*)d_in[4];
  const float* kdwp = (const float*)d_in[5];
  float* out = (float*)d_out;
  char*  ws  = (char*)d_ws;

  const size_t off_packed = 0;                                    // 8 MB
  const size_t off_ctrl   = (size_t)NROWS * NPIX * 4;
  const size_t off_gh8    = off_ctrl + CTRL_DW * 4;               // 8 KB
  const size_t off_gscnt  = off_gh8 + (size_t)NROWS * HB8 * 4;
  const size_t off_gsl3   = off_gscnt + (size_t)NROWS * 16 * 4;
  const size_t off_gstg   = off_gsl3 + (size_t)NROWS * 16 * 4;
  const size_t zero_end   = off_gstg + (size_t)NROWS * 16 * 4;
  const size_t off_sel    = (zero_end + 255) & ~(size_t)255;      // 2*NROWS u32
  const size_t off_pB3    = off_sel + 2 * NROWS * 4;
  const size_t off_pBT    = off_pB3 + (size_t)NROWS * KC_BPR * 4;
  const size_t off_pAT    = off_pBT + (size_t)NROWS * KC_BPR * 4;

  unsigned int* packed = (unsigned int*)(ws + off_packed);
  unsigned int* ctrl   = (unsigned int*)(ws + off_ctrl);
  unsigned int* gh8    = (unsigned int*)(ws + off_gh8);
  unsigned int* gscnt  = (unsigned int*)(ws + off_gscnt);
  float*        gsl3   = (float*)(ws + off_gsl3);
  unsigned int* gstg   = (unsigned int*)(ws + off_gstg);
  unsigned int* sP8    = (unsigned int*)(ws + off_sel);
  unsigned int* sKrem  = sP8 + NROWS;
  float*        pB3    = (float*)(ws + off_pB3);
  unsigned int* pBT    = (unsigned int*)(ws + off_pBT);
  unsigned int* pAT    = (unsigned int*)(ws + off_pAT);

  const int nzero = (int)((zero_end - off_ctrl) / 4);   // ctrl+gh8+sub-hists
  k_zero<<<4, 256, 0, stream>>>(ctrl, nzero);
  k_compute<<<NROWS * K1_BPR, 256, 0, stream>>>(in1, in2, in3, tgt, kdwp, frp,
                                                packed, gh8, ctrl, sP8, sKrem);
  k_collect<<<NROWS * KC_BPR, 256, 0, stream>>>(packed, sP8, sKrem, frp,
                                                pB3, pBT, pAT,
                                                gscnt, gsl3, gstg, ctrl, out);
}

// Round 9
// 46.505 us; speedup vs baseline: 2.5231x; 2.5231x over previous
//
#include <hip/hip_runtime.h>

#define NROWS  8
#define NPIX   262144         // 512*512
#define K1_BPR 256            // compute: 1024 px/block, grid 2048
#define KC_BPR 128            // collect: 2048 px/block, grid 1024
#define HB8    256            // 8-bit histogram bins per row

// monotonic float->uint map (ascending float == ascending uint)
__device__ __forceinline__ unsigned int fkey(float x){
  unsigned int u = __float_as_uint(x);
  return (u & 0x80000000u) ? ~u : (u | 0x80000000u);
}

// binary softmax with a single exp
__device__ __forceinline__ void softmax2(float a0, float a1,
    float& lp0, float& lp1, float& p0, float& p1){
  float d  = a1 - a0;
  float ad = -fabsf(d);
  float e  = __expf(ad);
  float s  = 1.0f + e;
  float ls = __logf(s);
  float rs = __builtin_amdgcn_rcpf(s);
  float lpM = -ls,  lpm = ad - ls;
  float pM  = rs,   pm  = e * rs;
  bool g = (d >= 0.0f);
  lp1 = g ? lpM : lpm;  lp0 = g ? lpm : lpM;
  p1  = g ? pM  : pm;   p0  = g ? pm  : pM;
}

__device__ __forceinline__ float focal2(float tt, float lp0, float lp1,
                                        float p0, float p1){
  float q1 = 1.0f - p1, q0 = 1.0f - p0;
  return -(tt * q1 * q1 * lp1) - ((1.0f - tt) * q0 * q0 * lp0);
}

__device__ __forceinline__ unsigned kTop(const float* frp){
  return (unsigned)((1.0 - (double)(*frp)) * (double)NPIX);   // 209715
}

// parallel 256-bin select (256 threads): returns (bin, kRem-within-bin)
__device__ __forceinline__ uint2 selectBinV(unsigned v, unsigned kRem,
    unsigned* cum, unsigned* res){
  const int t = threadIdx.x;
  cum[t] = v;
  if (t == 0){ res[0] = 255u; res[1] = kRem; }
  __syncthreads();
  unsigned run = v;
  #pragma unroll
  for (int off = 1; off < 256; off <<= 1){
    unsigned add = (t >= off) ? cum[t - off] : 0u;
    __syncthreads();
    run += add;
    cum[t] = run;
    __syncthreads();
  }
  unsigned inc = cum[t], exc = inc - v;
  if (exc < kRem && inc >= kRem) { res[0] = (unsigned)t; res[1] = kRem - exc; }
  __syncthreads();
  uint2 r = make_uint2(res[0], res[1]);
  __syncthreads();
  return r;
}

// custom zero (runtime fillBuffer is slow/unpredictable for small fills)
__global__ __launch_bounds__(256) void k_zero(unsigned int* __restrict__ p, int n){
  int i = blockIdx.x * 256 + threadIdx.x;
  int stride = gridDim.x * 256;
  for (; i < n; i += stride) p[i] = 0u;
}

// loss compute + pack + 256-bin wave-ballot LDS hist + aggregated flush.
// NO cross-block communication (per-block __threadfence() in rounds 6-8 cost
// 60-100us: device-scope release forces an L2 writeback on non-coherent
// per-XCD L2s, ~2048 serialized flushes). Kernel boundary = free coherence.
// Packed word: [31:20]=key12  [19]=target  [18:0]=l3 bits (exp8+man10, rnd)
__global__ __launch_bounds__(256) void k_compute(
    const float* __restrict__ in1, const float* __restrict__ in2,
    const float* __restrict__ in3, const int* __restrict__ tgt,
    const float* __restrict__ kdwp,
    unsigned int* __restrict__ packed, unsigned int* __restrict__ ghist)
{
  __shared__ unsigned lh[HB8];         // 1 KB block-local histogram
  const int t = threadIdx.x;
  lh[t] = 0;
  __syncthreads();

  const int blk   = blockIdx.x;
  const int row   = blk >> 8;                       // / K1_BPR
  const int chunk = (blk & (K1_BPR - 1)) * (NPIX / K1_BPR);
  const int base  = chunk + 4 * t;
  const float kdw = *kdwp;
  const float w1  = (float)(1.0 - (double)kdw);

  const size_t ro2 = (size_t)row * 2 * NPIX;
  const size_t ro1 = (size_t)row * NPIX;

  float4 x10 = *(const float4*)(in1 + ro2 + base);
  float4 x11 = *(const float4*)(in1 + ro2 + NPIX + base);
  float4 x20 = *(const float4*)(in2 + ro2 + base);
  float4 x21 = *(const float4*)(in2 + ro2 + NPIX + base);
  float4 x30 = *(const float4*)(in3 + ro2 + base);
  float4 x31 = *(const float4*)(in3 + ro2 + NPIX + base);
  int4   tg  = *(const int4*)(tgt + ro1 + base);

  float a10[4] = {x10.x, x10.y, x10.z, x10.w};
  float a11[4] = {x11.x, x11.y, x11.z, x11.w};
  float a20[4] = {x20.x, x20.y, x20.z, x20.w};
  float a21[4] = {x21.x, x21.y, x21.z, x21.w};
  float a30[4] = {x30.x, x30.y, x30.z, x30.w};
  float a31[4] = {x31.x, x31.y, x31.z, x31.w};
  int   tgv[4] = {tg.x, tg.y, tg.z, tg.w};

  unsigned pw[4];
  #pragma unroll
  for (int j = 0; j < 4; ++j){
    float tt = (float)tgv[j];
    float lp10, lp11, p10, p11; softmax2(a10[j], a11[j], lp10, lp11, p10, p11);
    float lp20, lp21, p20, p21; softmax2(a20[j], a21[j], lp20, lp21, p20, p21);
    float lp30, lp31, p30, p31; softmax2(a30[j], a31[j], lp30, lp31, p30, p31);
    float l1 = focal2(tt, lp10, lp11, p10, p11);
    float l2 = focal2(tt, lp20, lp21, p20, p21);
    float l3 = focal2(tt, lp30, lp31, p30, p31);
    float kdl12 = p10 * (lp10 - lp20) + p11 * (lp11 - lp21);
    float kdl21 = p20 * (lp20 - lp10) + p21 * (lp21 - lp11);
    float loss  = w1 * (l1 + l2 + l3) + kdw * (kdl12 + kdl21);
    unsigned k12 = fkey(loss) >> 20;
    // l3 >= 0: keep exp8+man10, round-to-nearest via +0x1000 before shift
    unsigned lb = __float_as_uint(l3) + 0x1000u;
    pw[j] = (k12 << 20) | (((unsigned)tgv[j]) << 19) | ((lb >> 13) & 0x7FFFFu);
  }
  *(uint4*)(packed + ro1 + base) = make_uint4(pw[0], pw[1], pw[2], pw[3]);

  // wave-ballot aggregated histogram: ONE LDS atomic per distinct bin/wave
  // (~10 exponent-level hot bins; per-pixel LDS atomics serialized in r6)
  const int lane = t & 63;
  #pragma unroll
  for (int j = 0; j < 4; ++j){
    unsigned bin = pw[j] >> 24;
    unsigned long long rem = ~0ull;
    while (rem){
      int lead = __ffsll(rem) - 1;
      unsigned leadBin = (unsigned)__shfl((int)bin, lead);
      unsigned long long same = __ballot(bin == leadBin);
      if (lane == lead) atomicAdd(&lh[leadBin], (unsigned)__popcll(same));
      rem &= ~same;
    }
  }
  __syncthreads();

  // flush block-local hist -> global (one aggregated atomic per hot bin)
  unsigned lv = lh[t];
  if (lv) atomicAdd(&ghist[row * HB8 + t], lv);
}

// collect: recompute threshold inline (cheap parallel scan over completed
// hist), below-bin sums + per-wave 16-sub-bin stats + per-block partials.
__global__ __launch_bounds__(256) void k_collect(
    const unsigned int* __restrict__ packed,
    const unsigned int* __restrict__ ghist,
    const float* __restrict__ frp,
    float* __restrict__ pB3, unsigned int* __restrict__ pBT,
    unsigned int* __restrict__ pAT,
    unsigned int* __restrict__ gscnt, float* __restrict__ gsl3,
    unsigned int* __restrict__ gstg)
{
  __shared__ unsigned cum[256];
  __shared__ unsigned res[2];
  __shared__ unsigned s_cnt[4][16];
  __shared__ float    s_l3[4][16];
  __shared__ unsigned s_tg[4][16];
  __shared__ float wf[4];
  __shared__ int   wi[8];
  const int t = threadIdx.x, lane = t & 63, wid = t >> 6;
  const int blk   = blockIdx.x;
  const int row   = blk >> 7;                       // / KC_BPR
  const int chunk = (blk & (KC_BPR - 1)) * (NPIX / KC_BPR);
  const size_t ro = (size_t)row * NPIX;
  if (t < 64){
    s_cnt[t >> 4][t & 15] = 0; s_l3[t >> 4][t & 15] = 0.0f;
    s_tg[t >> 4][t & 15] = 0;
  }
  uint2 s0 = selectBinV(ghist[row * HB8 + t], kTop(frp), cum, res);
  const unsigned T8 = s0.x;

  float b3 = 0.0f; int bt = 0, at = 0;
  #pragma unroll
  for (int it = 0; it < 2; ++it){
    int base = chunk + it * 1024 + 4 * t;
    uint4 w = *(const uint4*)(packed + ro + base);
    unsigned a[4] = {w.x, w.y, w.z, w.w};
    #pragma unroll
    for (int j = 0; j < 4; ++j){
      unsigned k8 = a[j] >> 24;
      float l3 = __uint_as_float((a[j] & 0x7FFFFu) << 13);
      int   tv = (int)((a[j] >> 19) & 1u);
      at += tv;
      if (k8 < T8){ b3 += l3; bt += tv; }
      else if (k8 == T8){
        unsigned sub = (a[j] >> 20) & 15u;     // key12 refinement
        atomicAdd(&s_cnt[wid][sub], 1u);       // per-wave copy: 4x less clash
        atomicAdd(&s_l3[wid][sub], l3);
        if (tv) atomicAdd(&s_tg[wid][sub], 1u);
      }
    }
  }
  #pragma unroll
  for (int o = 32; o; o >>= 1){
    b3 += __shfl_down(b3, o); bt += __shfl_down(bt, o); at += __shfl_down(at, o);
  }
  if (lane == 0){ wf[wid] = b3; wi[wid] = bt; wi[4 + wid] = at; }
  __syncthreads();
  if (t < 16){
    unsigned c = s_cnt[0][t] + s_cnt[1][t] + s_cnt[2][t] + s_cnt[3][t];
    float    l = s_l3[0][t] + s_l3[1][t] + s_l3[2][t] + s_l3[3][t];
    unsigned g = s_tg[0][t] + s_tg[1][t] + s_tg[2][t] + s_tg[3][t];
    if (c) atomicAdd(&gscnt[row * 16 + t], c);
    if (l != 0.0f) atomicAdd(&gsl3[row * 16 + t], l);
    if (g) atomicAdd(&gstg[row * 16 + t], g);
  }
  if (t == 0){
    pB3[blk] = wf[0] + wf[1] + wf[2] + wf[3];
    pBT[blk] = (unsigned)(wi[0] + wi[1] + wi[2] + wi[3]);
    pAT[blk] = (unsigned)(wi[4] + wi[5] + wi[6] + wi[7]);
  }
}

// single block: per-row tie fractions + reduce block partials -> out
__global__ __launch_bounds__(256) void k_final(
    const unsigned int* __restrict__ ghist, const float* __restrict__ frp,
    const unsigned int* __restrict__ gscnt, const float* __restrict__ gsl3,
    const unsigned int* __restrict__ gstg,
    const float* __restrict__ pB3, const unsigned int* __restrict__ pBT,
    const unsigned int* __restrict__ pAT, float* __restrict__ out)
{
  __shared__ unsigned cum[256];
  __shared__ unsigned res[2];
  __shared__ unsigned kremA[NROWS];
  __shared__ double dd[12];
  const int t = threadIdx.x, lane = t & 63, wid = t >> 6;
  const unsigned k0 = kTop(frp);

  for (int r = 0; r < NROWS; ++r){
    uint2 s0 = selectBinV(ghist[r * HB8 + t], k0, cum, res);
    if (t == 0) kremA[r] = s0.y;
  }
  __syncthreads();

  // per-row tie resolution (16 sub-bins, frac-weighted crossing bin)
  double tie3 = 0.0, tieT = 0.0;
  if (t < NROWS){
    const int r = t;
    const unsigned kRem = kremA[r];
    unsigned cum2 = 0;
    for (int s2 = 0; s2 < 16; ++s2){
      unsigned c = gscnt[r * 16 + s2];
      if (c){
        unsigned take = 0;
        if (kRem > cum2){
          unsigned avail = kRem - cum2;
          take = (avail < c) ? avail : c;
        }
        if (take){
          double fr = (double)take / (double)c;
          tie3 += fr * (double)gsl3[r * 16 + s2];
          tieT += fr * (double)gstg[r * 16 + s2];
        }
        cum2 += c;
      }
    }
  }

  double S3 = tie3, ST = tieT, TT = 0.0;
  for (int i = t; i < NROWS * KC_BPR; i += 256){
    S3 += (double)pB3[i]; ST += (double)pBT[i]; TT += (double)pAT[i];
  }
  #pragma unroll
  for (int o = 32; o; o >>= 1){
    S3 += __shfl_down(S3, o); ST += __shfl_down(ST, o); TT += __shfl_down(TT, o);
  }
  if (lane == 0){ dd[wid] = S3; dd[4 + wid] = ST; dd[8 + wid] = TT; }
  __syncthreads();
  if (t == 0){
    double s0 = dd[0] + dd[1] + dd[2] + dd[3];
    double s1 = dd[4] + dd[5] + dd[6] + dd[7];
    double st = dd[8] + dd[9] + dd[10] + dd[11];
    out[0] = (float)(s0 / ((double)NROWS * (double)k0));
    out[1] = (float)(s1 / st);
  }
}

extern "C" void kernel_launch(void* const* d_in, const int* in_sizes, int n_in,
                              void* d_out, int out_size, void* d_ws, size_t ws_size,
                              hipStream_t stream)
{
  const float* in1  = (const float*)d_in[0];
  const float* in2  = (const float*)d_in[1];
  const float* in3  = (const float*)d_in[2];
  const int*   tgt  = (const int*)d_in[3];
  const float* frp  = (const float*)d_in[4];
  const float* kdwp = (const float*)d_in[5];
  float* out = (float*)d_out;
  char*  ws  = (char*)d_ws;

  const size_t off_packed = 0;                                    // 8 MB
  const size_t off_gh8    = (size_t)NROWS * NPIX * 4;
  const size_t off_gscnt  = off_gh8 + (size_t)NROWS * HB8 * 4;
  const size_t off_gsl3   = off_gscnt + (size_t)NROWS * 16 * 4;
  const size_t off_gstg   = off_gsl3 + (size_t)NROWS * 16 * 4;
  const size_t zero_end   = off_gstg + (size_t)NROWS * 16 * 4;
  const size_t off_pB3    = (zero_end + 255) & ~(size_t)255;
  const size_t off_pBT    = off_pB3 + (size_t)NROWS * KC_BPR * 4;
  const size_t off_pAT    = off_pBT + (size_t)NROWS * KC_BPR * 4;

  unsigned int* packed = (unsigned int*)(ws + off_packed);
  unsigned int* gh8    = (unsigned int*)(ws + off_gh8);
  unsigned int* gscnt  = (unsigned int*)(ws + off_gscnt);
  float*        gsl3   = (float*)(ws + off_gsl3);
  unsigned int* gstg   = (unsigned int*)(ws + off_gstg);
  float*        pB3    = (float*)(ws + off_pB3);
  unsigned int* pBT    = (unsigned int*)(ws + off_pBT);
  unsigned int* pAT    = (unsigned int*)(ws + off_pAT);

  const int nzero = (int)((zero_end - off_gh8) / 4);   // gh8 + sub-hists
  k_zero<<<4, 256, 0, stream>>>(gh8, nzero);
  k_compute<<<NROWS * K1_BPR, 256, 0, stream>>>(in1, in2, in3, tgt, kdwp,
                                                packed, gh8);
  k_collect<<<NROWS * KC_BPR, 256, 0, stream>>>(packed, gh8, frp,
                                                pB3, pBT, pAT,
                                                gscnt, gsl3, gstg);
  k_final<<<1, 256, 0, stream>>>(gh8, frp, gscnt, gsl3, gstg,
                                 pB3, pBT, pAT, out);
}

// Round 10
// 44.878 us; speedup vs baseline: 2.6145x; 1.0362x over previous
//
#include <hip/hip_runtime.h>

#define NROWS  8
#define NPIX   262144         // 512*512
#define K1_BPR 256            // compute: 1024 px/block, grid 2048
#define KC_BPR 128            // collect: 2048 px/block, grid 1024
#define HB8    256            // 8-bit histogram bins per row
#define NSALT  16             // LDS histogram replication (bank-spread)
#define SSTRIDE 257           // copy stride: bank = (salt + bin) % 32

// monotonic float->uint map (ascending float == ascending uint)
__device__ __forceinline__ unsigned int fkey(float x){
  unsigned int u = __float_as_uint(x);
  return (u & 0x80000000u) ? ~u : (u | 0x80000000u);
}

// binary softmax with a single exp
__device__ __forceinline__ void softmax2(float a0, float a1,
    float& lp0, float& lp1, float& p0, float& p1){
  float d  = a1 - a0;
  float ad = -fabsf(d);
  float e  = __expf(ad);
  float s  = 1.0f + e;
  float ls = __logf(s);
  float rs = __builtin_amdgcn_rcpf(s);
  float lpM = -ls,  lpm = ad - ls;
  float pM  = rs,   pm  = e * rs;
  bool g = (d >= 0.0f);
  lp1 = g ? lpM : lpm;  lp0 = g ? lpm : lpM;
  p1  = g ? pM  : pm;   p0  = g ? pm  : pM;
}

__device__ __forceinline__ float focal2(float tt, float lp0, float lp1,
                                        float p0, float p1){
  float q1 = 1.0f - p1, q0 = 1.0f - p0;
  return -(tt * q1 * q1 * lp1) - ((1.0f - tt) * q0 * q0 * lp0);
}

__device__ __forceinline__ unsigned kTop(const float* frp){
  return (unsigned)((1.0 - (double)(*frp)) * (double)NPIX);   // 209715
}

// parallel 256-bin select (256 threads): returns (bin, kRem-within-bin)
__device__ __forceinline__ uint2 selectBinV(unsigned v, unsigned kRem,
    unsigned* cum, unsigned* res){
  const int t = threadIdx.x;
  cum[t] = v;
  if (t == 0){ res[0] = 255u; res[1] = kRem; }
  __syncthreads();
  unsigned run = v;
  #pragma unroll
  for (int off = 1; off < 256; off <<= 1){
    unsigned add = (t >= off) ? cum[t - off] : 0u;
    __syncthreads();
    run += add;
    cum[t] = run;
    __syncthreads();
  }
  unsigned inc = cum[t], exc = inc - v;
  if (exc < kRem && inc >= kRem) { res[0] = (unsigned)t; res[1] = kRem - exc; }
  __syncthreads();
  uint2 r = make_uint2(res[0], res[1]);
  __syncthreads();
  return r;
}

// custom zero (runtime fillBuffer is slow/unpredictable for small fills)
__global__ __launch_bounds__(256) void k_zero(unsigned int* __restrict__ p, int n){
  int i = blockIdx.x * 256 + threadIdx.x;
  int stride = gridDim.x * 256;
  for (; i < n; i += stride) p[i] = 0u;
}

// loss compute + pack + lane-salted 256-bin LDS hist + aggregated flush.
// Salting: 16 copies at stride 257 -> a hot bin's lanes spread over 16
// banks, <=2-way same-address (free). One LDS atomic per pixel vs the
// ballot loop's ~40 dependent shfl ops (r9) or 1-copy 30-way serialization
// (r6, 183K conflict cycles). No cross-block fences (r8 lesson: ~2K
// device-scope releases cost 60-100us on non-coherent per-XCD L2s).
// Packed word: [31:20]=key12  [19]=target  [18:0]=l3 bits (exp8+man10, rnd)
__global__ __launch_bounds__(256) void k_compute(
    const float* __restrict__ in1, const float* __restrict__ in2,
    const float* __restrict__ in3, const int* __restrict__ tgt,
    const float* __restrict__ kdwp,
    unsigned int* __restrict__ packed, unsigned int* __restrict__ ghist)
{
  __shared__ unsigned lh[NSALT * SSTRIDE];   // 16.4 KB salted histogram
  const int t = threadIdx.x;
  for (int i = t; i < NSALT * SSTRIDE; i += 256) lh[i] = 0;
  __syncthreads();

  const int blk   = blockIdx.x;
  const int row   = blk >> 8;                       // / K1_BPR
  const int chunk = (blk & (K1_BPR - 1)) * (NPIX / K1_BPR);
  const int base  = chunk + 4 * t;
  const float kdw = *kdwp;
  const float w1  = (float)(1.0 - (double)kdw);

  const size_t ro2 = (size_t)row * 2 * NPIX;
  const size_t ro1 = (size_t)row * NPIX;

  float4 x10 = *(const float4*)(in1 + ro2 + base);
  float4 x11 = *(const float4*)(in1 + ro2 + NPIX + base);
  float4 x20 = *(const float4*)(in2 + ro2 + base);
  float4 x21 = *(const float4*)(in2 + ro2 + NPIX + base);
  float4 x30 = *(const float4*)(in3 + ro2 + base);
  float4 x31 = *(const float4*)(in3 + ro2 + NPIX + base);
  int4   tg  = *(const int4*)(tgt + ro1 + base);

  float a10[4] = {x10.x, x10.y, x10.z, x10.w};
  float a11[4] = {x11.x, x11.y, x11.z, x11.w};
  float a20[4] = {x20.x, x20.y, x20.z, x20.w};
  float a21[4] = {x21.x, x21.y, x21.z, x21.w};
  float a30[4] = {x30.x, x30.y, x30.z, x30.w};
  float a31[4] = {x31.x, x31.y, x31.z, x31.w};
  int   tgv[4] = {tg.x, tg.y, tg.z, tg.w};

  const int salt = (t & (NSALT - 1)) * SSTRIDE;
  unsigned pw[4];
  #pragma unroll
  for (int j = 0; j < 4; ++j){
    float tt = (float)tgv[j];
    float lp10, lp11, p10, p11; softmax2(a10[j], a11[j], lp10, lp11, p10, p11);
    float lp20, lp21, p20, p21; softmax2(a20[j], a21[j], lp20, lp21, p20, p21);
    float lp30, lp31, p30, p31; softmax2(a30[j], a31[j], lp30, lp31, p30, p31);
    float l1 = focal2(tt, lp10, lp11, p10, p11);
    float l2 = focal2(tt, lp20, lp21, p20, p21);
    float l3 = focal2(tt, lp30, lp31, p30, p31);
    float kdl12 = p10 * (lp10 - lp20) + p11 * (lp11 - lp21);
    float kdl21 = p20 * (lp20 - lp10) + p21 * (lp21 - lp11);
    float loss  = w1 * (l1 + l2 + l3) + kdw * (kdl12 + kdl21);
    unsigned k12 = fkey(loss) >> 20;
    // l3 >= 0: keep exp8+man10, round-to-nearest via +0x1000 before shift
    unsigned lb = __float_as_uint(l3) + 0x1000u;
    pw[j] = (k12 << 20) | (((unsigned)tgv[j]) << 19) | ((lb >> 13) & 0x7FFFFu);
    atomicAdd(&lh[salt + (k12 >> 4)], 1u);     // 1 salted LDS atomic / pixel
  }
  *(uint4*)(packed + ro1 + base) = make_uint4(pw[0], pw[1], pw[2], pw[3]);

  __syncthreads();
  // reduce 16 copies (conflict-free: bank = (c+t)%32) -> aggregated flush
  unsigned v = 0;
  #pragma unroll
  for (int c = 0; c < NSALT; ++c) v += lh[c * SSTRIDE + t];
  if (v) atomicAdd(&ghist[row * HB8 + t], v);
}

// collect: recompute threshold inline (cheap parallel scan over completed
// hist), below-bin sums + per-wave 16-sub-bin stats + per-block partials.
__global__ __launch_bounds__(256) void k_collect(
    const unsigned int* __restrict__ packed,
    const unsigned int* __restrict__ ghist,
    const float* __restrict__ frp,
    float* __restrict__ pB3, unsigned int* __restrict__ pBT,
    unsigned int* __restrict__ pAT,
    unsigned int* __restrict__ gscnt, float* __restrict__ gsl3,
    unsigned int* __restrict__ gstg)
{
  __shared__ unsigned cum[256];
  __shared__ unsigned res[2];
  __shared__ unsigned s_cnt[4][16];
  __shared__ float    s_l3[4][16];
  __shared__ unsigned s_tg[4][16];
  __shared__ float wf[4];
  __shared__ int   wi[8];
  const int t = threadIdx.x, lane = t & 63, wid = t >> 6;
  const int blk   = blockIdx.x;
  const int row   = blk >> 7;                       // / KC_BPR
  const int chunk = (blk & (KC_BPR - 1)) * (NPIX / KC_BPR);
  const size_t ro = (size_t)row * NPIX;
  if (t < 64){
    s_cnt[t >> 4][t & 15] = 0; s_l3[t >> 4][t & 15] = 0.0f;
    s_tg[t >> 4][t & 15] = 0;
  }
  uint2 s0 = selectBinV(ghist[row * HB8 + t], kTop(frp), cum, res);
  const unsigned T8 = s0.x;

  float b3 = 0.0f; int bt = 0, at = 0;
  #pragma unroll
  for (int it = 0; it < 2; ++it){
    int base = chunk + it * 1024 + 4 * t;
    uint4 w = *(const uint4*)(packed + ro + base);
    unsigned a[4] = {w.x, w.y, w.z, w.w};
    #pragma unroll
    for (int j = 0; j < 4; ++j){
      unsigned k8 = a[j] >> 24;
      float l3 = __uint_as_float((a[j] & 0x7FFFFu) << 13);
      int   tv = (int)((a[j] >> 19) & 1u);
      at += tv;
      if (k8 < T8){ b3 += l3; bt += tv; }
      else if (k8 == T8){
        unsigned sub = (a[j] >> 20) & 15u;     // key12 refinement
        atomicAdd(&s_cnt[wid][sub], 1u);       // per-wave copy: 4x less clash
        atomicAdd(&s_l3[wid][sub], l3);
        if (tv) atomicAdd(&s_tg[wid][sub], 1u);
      }
    }
  }
  #pragma unroll
  for (int o = 32; o; o >>= 1){
    b3 += __shfl_down(b3, o); bt += __shfl_down(bt, o); at += __shfl_down(at, o);
  }
  if (lane == 0){ wf[wid] = b3; wi[wid] = bt; wi[4 + wid] = at; }
  __syncthreads();
  if (t < 16){
    unsigned c = s_cnt[0][t] + s_cnt[1][t] + s_cnt[2][t] + s_cnt[3][t];
    float    l = s_l3[0][t] + s_l3[1][t] + s_l3[2][t] + s_l3[3][t];
    unsigned g = s_tg[0][t] + s_tg[1][t] + s_tg[2][t] + s_tg[3][t];
    if (c) atomicAdd(&gscnt[row * 16 + t], c);
    if (l != 0.0f) atomicAdd(&gsl3[row * 16 + t], l);
    if (g) atomicAdd(&gstg[row * 16 + t], g);
  }
  if (t == 0){
    pB3[blk] = wf[0] + wf[1] + wf[2] + wf[3];
    pBT[blk] = (unsigned)(wi[0] + wi[1] + wi[2] + wi[3]);
    pAT[blk] = (unsigned)(wi[4] + wi[5] + wi[6] + wi[7]);
  }
}

// single block: per-row tie fractions + reduce block partials -> out
__global__ __launch_bounds__(256) void k_final(
    const unsigned int* __restrict__ ghist, const float* __restrict__ frp,
    const unsigned int* __restrict__ gscnt, const float* __restrict__ gsl3,
    const unsigned int* __restrict__ gstg,
    const float* __restrict__ pB3, const unsigned int* __restrict__ pBT,
    const unsigned int* __restrict__ pAT, float* __restrict__ out)
{
  __shared__ unsigned cum[256];
  __shared__ unsigned res[2];
  __shared__ unsigned kremA[NROWS];
  __shared__ double dd[12];
  const int t = threadIdx.x, lane = t & 63, wid = t >> 6;
  const unsigned k0 = kTop(frp);

  for (int r = 0; r < NROWS; ++r){
    uint2 s0 = selectBinV(ghist[r * HB8 + t], k0, cum, res);
    if (t == 0) kremA[r] = s0.y;
  }
  __syncthreads();

  // per-row tie resolution (16 sub-bins, frac-weighted crossing bin)
  double tie3 = 0.0, tieT = 0.0;
  if (t < NROWS){
    const int r = t;
    const unsigned kRem = kremA[r];
    unsigned cum2 = 0;
    for (int s2 = 0; s2 < 16; ++s2){
      unsigned c = gscnt[r * 16 + s2];
      if (c){
        unsigned take = 0;
        if (kRem > cum2){
          unsigned avail = kRem - cum2;
          take = (avail < c) ? avail : c;
        }
        if (take){
          double fr = (double)take / (double)c;
          tie3 += fr * (double)gsl3[r * 16 + s2];
          tieT += fr * (double)gstg[r * 16 + s2];
        }
        cum2 += c;
      }
    }
  }

  double S3 = tie3, ST = tieT, TT = 0.0;
  for (int i = t; i < NROWS * KC_BPR; i += 256){
    S3 += (double)pB3[i]; ST += (double)pBT[i]; TT += (double)pAT[i];
  }
  #pragma unroll
  for (int o = 32; o; o >>= 1){
    S3 += __shfl_down(S3, o); ST += __shfl_down(ST, o); TT += __shfl_down(TT, o);
  }
  if (lane == 0){ dd[wid] = S3; dd[4 + wid] = ST; dd[8 + wid] = TT; }
  __syncthreads();
  if (t == 0){
    double s0 = dd[0] + dd[1] + dd[2] + dd[3];
    double s1 = dd[4] + dd[5] + dd[6] + dd[7];
    double st = dd[8] + dd[9] + dd[10] + dd[11];
    out[0] = (float)(s0 / ((double)NROWS * (double)k0));
    out[1] = (float)(s1 / st);
  }
}

extern "C" void kernel_launch(void* const* d_in, const int* in_sizes, int n_in,
                              void* d_out, int out_size, void* d_ws, size_t ws_size,
                              hipStream_t stream)
{
  const float* in1  = (const float*)d_in[0];
  const float* in2  = (const float*)d_in[1];
  const float* in3  = (const float*)d_in[2];
  const int*   tgt  = (const int*)d_in[3];
  const float* frp  = (const float*)d_in[4];
  const float* kdwp = (const float*)d_in[5];
  float* out = (float*)d_out;
  char*  ws  = (char*)d_ws;

  const size_t off_packed = 0;                                    // 8 MB
  const size_t off_gh8    = (size_t)NROWS * NPIX * 4;
  const size_t off_gscnt  = off_gh8 + (size_t)NROWS * HB8 * 4;
  const size_t off_gsl3   = off_gscnt + (size_t)NROWS * 16 * 4;
  const size_t off_gstg   = off_gsl3 + (size_t)NROWS * 16 * 4;
  const size_t zero_end   = off_gstg + (size_t)NROWS * 16 * 4;
  const size_t off_pB3    = (zero_end + 255) & ~(size_t)255;
  const size_t off_pBT    = off_pB3 + (size_t)NROWS * KC_BPR * 4;
  const size_t off_pAT    = off_pBT + (size_t)NROWS * KC_BPR * 4;

  unsigned int* packed = (unsigned int*)(ws + off_packed);
  unsigned int* gh8    = (unsigned int*)(ws + off_gh8);
  unsigned int* gscnt  = (unsigned int*)(ws + off_gscnt);
  float*        gsl3   = (float*)(ws + off_gsl3);
  unsigned int* gstg   = (unsigned int*)(ws + off_gstg);
  float*        pB3    = (float*)(ws + off_pB3);
  unsigned int* pBT    = (unsigned int*)(ws + off_pBT);
  unsigned int* pAT    = (unsigned int*)(ws + off_pAT);

  const int nzero = (int)((zero_end - off_gh8) / 4);   // gh8 + sub-hists
  k_zero<<<4, 256, 0, stream>>>(gh8, nzero);
  k_compute<<<NROWS * K1_BPR, 256, 0, stream>>>(in1, in2, in3, tgt, kdwp,
                                                packed, gh8);
  k_collect<<<NROWS * KC_BPR, 256, 0, stream>>>(packed, gh8, frp,
                                                pB3, pBT, pAT,
                                                gscnt, gsl3, gstg);
  k_final<<<1, 256, 0, stream>>>(gh8, frp, gscnt, gsl3, gstg,
                                 pB3, pBT, pAT, out);
}